// Round 1
// baseline (2353.890 us; speedup 1.0000x reference)
//
#include <hip/hip_runtime.h>

#define NN 50000
#define NN0 30000
#define NN1 20000
#define NE 600000
#define INC 128
#define HIDC 128
#define OUTC 40
#define RS 1152      // A row stride: 8*128 agg + 128 feat
#define KST 36       // K steps of 32 (1152/32)

typedef __attribute__((ext_vector_type(4))) float f32x4;
typedef __attribute__((ext_vector_type(8))) short s16x8;

static __device__ __forceinline__ short f2bf(float f){
  unsigned u = __builtin_bit_cast(unsigned, f);
  u = u + 0x7fffu + ((u >> 16) & 1u);
  return (short)(u >> 16);
}

// zero cols [0,1024) of every row of A
__global__ void zerohead_k(float* __restrict__ A){
  int tid = blockIdx.x * 256 + threadIdx.x;   // NN*256 float4-slots
  int n = tid >> 8, q = tid & 255;
  if(n >= NN) return;
  *(float4*)(A + (size_t)n * RS + q * 4) = make_float4(0.f, 0.f, 0.f, 0.f);
}

// gather input features into A[:,1024:1152]
__global__ void xbuild_k(const float* __restrict__ x0, const float* __restrict__ e1,
                         const int* __restrict__ ntp, const int* __restrict__ lix,
                         float* __restrict__ A){
  int tid = blockIdx.x * 256 + threadIdx.x;   // NN*32
  int n = tid >> 5, q = tid & 31;
  if(n >= NN) return;
  int t = ntp[n], li = lix[n];
  const float* s;
  if(t == 0){ li = li < 0 ? 0 : (li > NN0 - 1 ? NN0 - 1 : li); s = x0 + (size_t)li * INC; }
  else      { li = li < 0 ? 0 : (li > NN1 - 1 ? NN1 - 1 : li); s = e1 + (size_t)li * INC; }
  float4 v = ((const float4*)s)[q];
  *(float4*)(A + (size_t)n * RS + 1024 + q * 4) = v;
}

__global__ void count_k(const int* __restrict__ ei, const int* __restrict__ et, int* __restrict__ cnt){
  int e = blockIdx.x * 256 + threadIdx.x;
  if(e >= NE) return;
  atomicAdd(&cnt[(size_t)ei[NE + e] * 8 + et[e]], 1);
}

__global__ void inv_k(const int* __restrict__ cnt, float* __restrict__ inv){
  int i = blockIdx.x * 256 + threadIdx.x;
  if(i >= NN * 8) return;
  int c = cnt[i];
  inv[i] = 1.0f / (float)(c > 1 ? c : 1);
}

// per edge: A[dst, t*128 : t*128+128] += A[src, 1024:1152]   (32 lanes/edge, 4 floats/lane)
__global__ void scatter_k(const int* __restrict__ ei, const int* __restrict__ et, float* __restrict__ A){
  int gid = blockIdx.x * 256 + threadIdx.x;   // NE*32
  int e = gid >> 5, l = gid & 31;
  if(e >= NE) return;
  int s = ei[e], d = ei[NE + e], t = et[e];
  float4 v = *(const float4*)(A + (size_t)s * RS + 1024 + l * 4);
  float* p = A + (size_t)d * RS + t * 128 + l * 4;
  atomicAdd(p + 0, v.x); atomicAdd(p + 1, v.y); atomicAdd(p + 2, v.z); atomicAdd(p + 3, v.w);
}

// pack B1: [v][ks][j(8)][lane(64)][8] bf16 ; B[k][n] = W[n][k]; k>=1024 -> root_w[v]
__global__ void pack1_k(const float* __restrict__ rw, const float* __restrict__ qw, short* __restrict__ Bp){
  int tid = blockIdx.x * 256 + threadIdx.x;
  if(tid >= 2 * KST * 8 * 64) return;
  int l = tid & 63, j = (tid >> 6) & 7, ks = (tid >> 9) % KST, v = (tid >> 9) / KST;
  int n = j * 16 + (l & 15);
  int kb = ks * 32 + (l >> 4) * 8;
  s16x8 ov;
  #pragma unroll
  for(int jj = 0; jj < 8; jj++){
    int k = kb + jj; float wv;
    if(k < 1024){ int t = k >> 7, ki = k & 127; wv = rw[((size_t)t * HIDC + n) * INC + ki]; }
    else        { wv = qw[((size_t)v * HIDC + n) * INC + (k - 1024)]; }
    ov[jj] = f2bf(wv);
  }
  ((s16x8*)Bp)[tid] = ov;
}

// pack B2: [v][ks][j(3)][lane(64)][8] bf16 ; cols >= 40 are zero
__global__ void pack2_k(const float* __restrict__ rw, const float* __restrict__ qw, short* __restrict__ Bp){
  int tid = blockIdx.x * 256 + threadIdx.x;
  if(tid >= 2 * KST * 3 * 64) return;
  int l = tid & 63;
  int q = tid >> 6;
  int j = q % 3; q /= 3;
  int ks = q % KST, v = q / KST;
  int n = j * 16 + (l & 15);
  int kb = ks * 32 + (l >> 4) * 8;
  s16x8 ov;
  #pragma unroll
  for(int jj = 0; jj < 8; jj++){
    int k = kb + jj; float wv = 0.f;
    if(n < OUTC){
      if(k < 1024){ int t = k >> 7, ki = k & 127; wv = rw[((size_t)t * OUTC + n) * INC + ki]; }
      else        { wv = qw[((size_t)v * OUTC + n) * INC + (k - 1024)]; }
    }
    ov[jj] = f2bf(wv);
  }
  ((s16x8*)Bp)[tid] = ov;
}

// GEMM1: h = relu(A_scaled @ B1^T + b1) written into A[:,1024:1152]. 64 rows/block, 4 waves.
__global__ __launch_bounds__(256) void gemm1_k(float* __restrict__ A, const s16x8* __restrict__ Bp,
                                               const float* __restrict__ inv, const float* __restrict__ rb,
                                               int nb0){
  int b = blockIdx.x;
  int v, rowbase, rowlim;
  if(b < nb0){ v = 0; rowbase = b * 64; rowlim = NN0; }
  else       { v = 1; rowbase = NN0 + (b - nb0) * 64; rowlim = NN; }
  int w = threadIdx.x >> 6, l = threadIdx.x & 63;
  int lm = l & 15, lk = l >> 4;
  int mrow = rowbase + w * 16 + lm;
  int mc = mrow < NN ? mrow : NN - 1;
  const float* arow = A + (size_t)mc * RS;
  const float* invr = inv + (size_t)mc * 8;
  const s16x8* bv = Bp + (size_t)v * (KST * 8 * 64);

  f32x4 acc[8];
  #pragma unroll
  for(int j = 0; j < 8; j++) acc[j] = (f32x4)(0.f);

  for(int ks = 0; ks < KST; ks++){
    const float* ap = arow + ks * 32 + lk * 8;
    float4 a0 = *(const float4*)ap;
    float4 a1 = *(const float4*)(ap + 4);
    float sc = ks < 32 ? invr[ks >> 2] : 1.0f;
    s16x8 af;
    af[0] = f2bf(a0.x * sc); af[1] = f2bf(a0.y * sc); af[2] = f2bf(a0.z * sc); af[3] = f2bf(a0.w * sc);
    af[4] = f2bf(a1.x * sc); af[5] = f2bf(a1.y * sc); af[6] = f2bf(a1.z * sc); af[7] = f2bf(a1.w * sc);
    const s16x8* bk = bv + (size_t)ks * (8 * 64) + l;
    #pragma unroll
    for(int j = 0; j < 8; j++)
      acc[j] = __builtin_amdgcn_mfma_f32_16x16x32_bf16(af, bk[j * 64], acc[j], 0, 0, 0);
  }
  #pragma unroll
  for(int j = 0; j < 8; j++){
    int col = j * 16 + lm;
    float bias = rb[v * HIDC + col];
    #pragma unroll
    for(int r = 0; r < 4; r++){
      int row = rowbase + w * 16 + lk * 4 + r;
      if(row < rowlim){
        float hv = acc[j][r] + bias;
        A[(size_t)row * RS + 1024 + col] = hv > 0.f ? hv : 0.f;
      }
    }
  }
}

// GEMM2 + bias + log_softmax -> out
__global__ __launch_bounds__(256) void gemm2_k(const float* __restrict__ A, const s16x8* __restrict__ Bp,
                                               const float* __restrict__ inv, const float* __restrict__ rb,
                                               float* __restrict__ out, int nb0){
  int b = blockIdx.x;
  int v, rowbase, rowlim;
  if(b < nb0){ v = 0; rowbase = b * 64; rowlim = NN0; }
  else       { v = 1; rowbase = NN0 + (b - nb0) * 64; rowlim = NN; }
  int w = threadIdx.x >> 6, l = threadIdx.x & 63;
  int lm = l & 15, lk = l >> 4;
  int mrow = rowbase + w * 16 + lm;
  int mc = mrow < NN ? mrow : NN - 1;
  const float* arow = A + (size_t)mc * RS;
  const float* invr = inv + (size_t)mc * 8;
  const s16x8* bv = Bp + (size_t)v * (KST * 3 * 64);

  f32x4 acc[3];
  #pragma unroll
  for(int j = 0; j < 3; j++) acc[j] = (f32x4)(0.f);

  for(int ks = 0; ks < KST; ks++){
    const float* ap = arow + ks * 32 + lk * 8;
    float4 a0 = *(const float4*)ap;
    float4 a1 = *(const float4*)(ap + 4);
    float sc = ks < 32 ? invr[ks >> 2] : 1.0f;
    s16x8 af;
    af[0] = f2bf(a0.x * sc); af[1] = f2bf(a0.y * sc); af[2] = f2bf(a0.z * sc); af[3] = f2bf(a0.w * sc);
    af[4] = f2bf(a1.x * sc); af[5] = f2bf(a1.y * sc); af[6] = f2bf(a1.z * sc); af[7] = f2bf(a1.w * sc);
    const s16x8* bk = bv + (size_t)ks * (3 * 64) + l;
    #pragma unroll
    for(int j = 0; j < 3; j++)
      acc[j] = __builtin_amdgcn_mfma_f32_16x16x32_bf16(af, bk[j * 64], acc[j], 0, 0, 0);
  }

  float vals[3][4];
  #pragma unroll
  for(int j = 0; j < 3; j++){
    int col = j * 16 + lm;
    float bias = col < OUTC ? rb[v * OUTC + col] : 0.f;
    #pragma unroll
    for(int r = 0; r < 4; r++) vals[j][r] = acc[j][r] + bias;
  }
  float mx[4], se[4];
  #pragma unroll
  for(int r = 0; r < 4; r++){
    float m = -1e30f;
    #pragma unroll
    for(int j = 0; j < 3; j++) if(j * 16 + lm < OUTC) m = fmaxf(m, vals[j][r]);
    mx[r] = m;
  }
  #pragma unroll
  for(int s = 1; s < 16; s <<= 1){
    #pragma unroll
    for(int r = 0; r < 4; r++) mx[r] = fmaxf(mx[r], __shfl_xor(mx[r], s, 64));
  }
  #pragma unroll
  for(int r = 0; r < 4; r++){
    float a = 0.f;
    #pragma unroll
    for(int j = 0; j < 3; j++) if(j * 16 + lm < OUTC) a += __expf(vals[j][r] - mx[r]);
    se[r] = a;
  }
  #pragma unroll
  for(int s = 1; s < 16; s <<= 1){
    #pragma unroll
    for(int r = 0; r < 4; r++) se[r] += __shfl_xor(se[r], s, 64);
  }
  #pragma unroll
  for(int r = 0; r < 4; r++) se[r] = logf(se[r]);
  #pragma unroll
  for(int j = 0; j < 3; j++){
    int col = j * 16 + lm;
    if(col >= OUTC) continue;
    #pragma unroll
    for(int r = 0; r < 4; r++){
      int row = rowbase + w * 16 + lk * 4 + r;
      if(row < rowlim) out[(size_t)row * OUTC + col] = vals[j][r] - mx[r] - se[r];
    }
  }
}

extern "C" void kernel_launch(void* const* d_in, const int* in_sizes, int n_in,
                              void* d_out, int out_size, void* d_ws, size_t ws_size,
                              hipStream_t stream){
  const float* x0  = (const float*)d_in[0];
  const float* e1  = (const float*)d_in[1];
  const float* rw1 = (const float*)d_in[2];
  const float* qw1 = (const float*)d_in[3];
  const float* qb1 = (const float*)d_in[4];
  const float* rw2 = (const float*)d_in[5];
  const float* qw2 = (const float*)d_in[6];
  const float* qb2 = (const float*)d_in[7];
  const int*   ei  = (const int*)d_in[8];
  const int*   et  = (const int*)d_in[9];
  const int*   ntp = (const int*)d_in[10];
  const int*   lix = (const int*)d_in[11];
  float* out = (float*)d_out;

  const size_t A_OFF = 0;                       // 50000*1152*4 = 230,400,000
  const size_t CNT_OFF = 230400000;             // 1,600,000
  const size_t INV_OFF = 232000000;             // 1,600,000
  const size_t BP1_OFF = 233600000;             // 589,824
  const size_t BP2_OFF = 234189824;             // 221,184
  const size_t TOTAL   = 234411008;
  if(ws_size < TOTAL) return;

  char* ws = (char*)d_ws;
  float* A   = (float*)(ws + A_OFF);
  int*   cnt = (int*)(ws + CNT_OFF);
  float* inv = (float*)(ws + INV_OFF);
  short* Bp1 = (short*)(ws + BP1_OFF);
  short* Bp2 = (short*)(ws + BP2_OFF);

  int nb0 = (NN0 + 63) / 64;                    // 469
  int nb1 = (NN - NN0 + 63) / 64;               // 313

  hipMemsetAsync(cnt, 0, (size_t)NN * 8 * 4, stream);
  pack1_k<<<(2 * KST * 8 * 64) / 256, 256, 0, stream>>>(rw1, qw1, Bp1);
  pack2_k<<<(2 * KST * 3 * 64 + 255) / 256, 256, 0, stream>>>(rw2, qw2, Bp2);
  zerohead_k<<<NN, 256, 0, stream>>>(A);
  xbuild_k<<<(NN * 32) / 256, 256, 0, stream>>>(x0, e1, ntp, lix, A);
  count_k<<<(NE + 255) / 256, 256, 0, stream>>>(ei, et, cnt);
  inv_k<<<(NN * 8 + 255) / 256, 256, 0, stream>>>(cnt, inv);
  scatter_k<<<(NE * 32) / 256, 256, 0, stream>>>(ei, et, A);
  gemm1_k<<<nb0 + nb1, 256, 0, stream>>>(A, (const s16x8*)Bp1, inv, qb1, nb0);
  zerohead_k<<<NN, 256, 0, stream>>>(A);
  scatter_k<<<(NE * 32) / 256, 256, 0, stream>>>(ei, et, A);
  gemm2_k<<<nb0 + nb1, 256, 0, stream>>>(A, (const s16x8*)Bp2, inv, qb2, out, nb0);
}

// Round 2
// 373.324 us; speedup vs baseline: 6.3052x; 6.3052x over previous
//
#include <hip/hip_runtime.h>

#define NN 50000
#define NN0 30000
#define NN1 20000
#define NE 600000
#define INC 128
#define HIDC 128
#define OUTC 40
#define RS 1152      // A row stride in bf16 elems: 8*128 agg + 128 feat
#define RSB 2304     // row stride bytes
#define KST 36       // K steps of 32 (1152/32)
#define CAP 64       // bucket capacity per dst
#define OVCAP 65536

typedef __attribute__((ext_vector_type(4))) float f32x4;
typedef __attribute__((ext_vector_type(8))) short s16x8;

static __device__ __forceinline__ unsigned short f2bf(float f){
  unsigned u = __builtin_bit_cast(unsigned, f);
  u = u + 0x7fffu + ((u >> 16) & 1u);
  return (unsigned short)(u >> 16);
}
static __device__ __forceinline__ float bflo(unsigned w){
  return __builtin_bit_cast(float, w << 16);
}
static __device__ __forceinline__ float bfhi(unsigned w){
  return __builtin_bit_cast(float, w & 0xffff0000u);
}

// gather input features into A tail (bf16). thread = (node, 8-ch group)
__global__ void xbuild_k(const float* __restrict__ x0, const float* __restrict__ e1,
                         const int* __restrict__ ntp, const int* __restrict__ lix,
                         char* __restrict__ A){
  int tid = blockIdx.x * 256 + threadIdx.x;   // NN*16
  int n = tid >> 4, q = tid & 15;
  if(n >= NN) return;
  int t = ntp[n], li = lix[n];
  const float* s;
  if(t == 0){ li = li < 0 ? 0 : (li > NN0 - 1 ? NN0 - 1 : li); s = x0 + (size_t)li * INC; }
  else      { li = li < 0 ? 0 : (li > NN1 - 1 ? NN1 - 1 : li); s = e1 + (size_t)li * INC; }
  float4 a = ((const float4*)s)[q * 2];
  float4 b = ((const float4*)s)[q * 2 + 1];
  uint4 o;
  o.x = (unsigned)f2bf(a.x) | ((unsigned)f2bf(a.y) << 16);
  o.y = (unsigned)f2bf(a.z) | ((unsigned)f2bf(a.w) << 16);
  o.z = (unsigned)f2bf(b.x) | ((unsigned)f2bf(b.y) << 16);
  o.w = (unsigned)f2bf(b.z) | ((unsigned)f2bf(b.w) << 16);
  *(uint4*)(A + (size_t)n * RSB + 2048 + q * 16) = o;
}

// per edge: count (dst,type), append to dst bucket (or overflow list)
__global__ void fill_k(const int* __restrict__ ei, const int* __restrict__ et,
                       int* __restrict__ cnt, int* __restrict__ deg,
                       int* __restrict__ eb, int* __restrict__ ovf, int* __restrict__ ovc){
  int e = blockIdx.x * 256 + threadIdx.x;
  if(e >= NE) return;
  int s = ei[e], d = ei[NE + e], t = et[e];
  atomicAdd(&cnt[d * 8 + t], 1);
  int pos = atomicAdd(&deg[d], 1);
  if(pos < CAP) eb[d * CAP + pos] = s | (t << 16);
  else { int oi = atomicAdd(ovc, 1); if(oi < OVCAP) ovf[oi] = e; }
}

__global__ void inv_k(const int* __restrict__ cnt, float* __restrict__ inv){
  int i = blockIdx.x * 256 + threadIdx.x;
  if(i >= NN * 8) return;
  int c = cnt[i];
  inv[i] = 1.0f / (float)(c > 1 ? c : 1);
}

// one wave per dst: accumulate per-type sums of src features (bf16 tail),
// scale by inv, write 8x128 bf16 aggregate into A head.
__global__ __launch_bounds__(256) void agg_k(const int* __restrict__ eb, const int* __restrict__ deg,
                                             const float* __restrict__ inv, char* __restrict__ A,
                                             const int* __restrict__ ovf, const int* __restrict__ ovc,
                                             const int* __restrict__ ei, const int* __restrict__ et){
  int wid = (blockIdx.x * 256 + threadIdx.x) >> 6;
  int l = threadIdx.x & 63;
  if(wid >= NN) return;
  int d = wid;
  int dg = deg[d];
  int nb = dg < CAP ? dg : CAP;
  int ent = eb[d * CAP + l];   // lane l holds bucket entry l (coalesced)
  float acc[16];
  #pragma unroll
  for(int j = 0; j < 16; j++) acc[j] = 0.f;
  for(int i = 0; i < nb; i++){
    int p = __shfl(ent, i, 64);
    int s = p & 0xffff, t = p >> 16;
    unsigned w = *(const unsigned*)(A + (size_t)s * RSB + 2048 + l * 4);
    float fx = bflo(w), fy = bfhi(w);
    #pragma unroll
    for(int tt = 0; tt < 8; tt++){
      float m = (tt == t) ? 1.0f : 0.0f;
      acc[2 * tt]     += m * fx;
      acc[2 * tt + 1] += m * fy;
    }
  }
  if(dg > CAP){
    int oc = *ovc; if(oc > OVCAP) oc = OVCAP;
    for(int i = 0; i < oc; i++){
      int e = ovf[i];
      if(ei[NE + e] != d) continue;
      int s = ei[e], t = et[e];
      unsigned w = *(const unsigned*)(A + (size_t)s * RSB + 2048 + l * 4);
      float fx = bflo(w), fy = bfhi(w);
      #pragma unroll
      for(int tt = 0; tt < 8; tt++){
        float m = (tt == t) ? 1.0f : 0.0f;
        acc[2 * tt]     += m * fx;
        acc[2 * tt + 1] += m * fy;
      }
    }
  }
  #pragma unroll
  for(int tt = 0; tt < 8; tt++){
    float iv = inv[d * 8 + tt];
    unsigned o = (unsigned)f2bf(acc[2 * tt] * iv) | ((unsigned)f2bf(acc[2 * tt + 1] * iv) << 16);
    *(unsigned*)(A + (size_t)d * RSB + tt * 256 + l * 4) = o;
  }
}

// pack B1: [v][ks][j(8)][lane(64)][8] bf16 ; B[k][n] = W[n][k]; k>=1024 -> root_w[v]
__global__ void pack1_k(const float* __restrict__ rw, const float* __restrict__ qw, short* __restrict__ Bp){
  int tid = blockIdx.x * 256 + threadIdx.x;
  if(tid >= 2 * KST * 8 * 64) return;
  int l = tid & 63, j = (tid >> 6) & 7, ks = (tid >> 9) % KST, v = (tid >> 9) / KST;
  int n = j * 16 + (l & 15);
  int kb = ks * 32 + (l >> 4) * 8;
  s16x8 ov;
  #pragma unroll
  for(int jj = 0; jj < 8; jj++){
    int k = kb + jj; float wv;
    if(k < 1024){ int t = k >> 7, ki = k & 127; wv = rw[((size_t)t * HIDC + n) * INC + ki]; }
    else        { wv = qw[((size_t)v * HIDC + n) * INC + (k - 1024)]; }
    ov[jj] = (short)f2bf(wv);
  }
  ((s16x8*)Bp)[tid] = ov;
}

// pack B2: [v][ks][j(3)][lane(64)][8] bf16 ; cols >= 40 are zero
__global__ void pack2_k(const float* __restrict__ rw, const float* __restrict__ qw, short* __restrict__ Bp){
  int tid = blockIdx.x * 256 + threadIdx.x;
  if(tid >= 2 * KST * 3 * 64) return;
  int l = tid & 63;
  int q = tid >> 6;
  int j = q % 3; q /= 3;
  int ks = q % KST, v = q / KST;
  int n = j * 16 + (l & 15);
  int kb = ks * 32 + (l >> 4) * 8;
  s16x8 ov;
  #pragma unroll
  for(int jj = 0; jj < 8; jj++){
    int k = kb + jj; float wv = 0.f;
    if(n < OUTC){
      if(k < 1024){ int t = k >> 7, ki = k & 127; wv = rw[((size_t)t * OUTC + n) * INC + ki]; }
      else        { wv = qw[((size_t)v * OUTC + n) * INC + (k - 1024)]; }
    }
    ov[jj] = (short)f2bf(wv);
  }
  ((s16x8*)Bp)[tid] = ov;
}

// GEMM1: h = relu(A @ B1^T + b1) written into A tail (bf16). 64 rows/block, 4 waves.
__global__ __launch_bounds__(256) void gemm1_k(char* __restrict__ A, const s16x8* __restrict__ Bp,
                                               const float* __restrict__ rb, int nb0){
  int b = blockIdx.x;
  int v, rowbase, rowlim;
  if(b < nb0){ v = 0; rowbase = b * 64; rowlim = NN0; }
  else       { v = 1; rowbase = NN0 + (b - nb0) * 64; rowlim = NN; }
  int w = threadIdx.x >> 6, l = threadIdx.x & 63;
  int lm = l & 15, lk = l >> 4;
  int mrow = rowbase + w * 16 + lm;
  int mc = mrow < NN ? mrow : NN - 1;
  const char* arow = A + (size_t)mc * RSB;
  const s16x8* bv = Bp + (size_t)v * (KST * 8 * 64);

  f32x4 acc[8];
  #pragma unroll
  for(int j = 0; j < 8; j++) acc[j] = (f32x4)(0.f);

  for(int ks = 0; ks < KST; ks++){
    s16x8 af = *(const s16x8*)(arow + ks * 64 + lk * 16);
    const s16x8* bk = bv + (size_t)ks * (8 * 64) + l;
    #pragma unroll
    for(int j = 0; j < 8; j++)
      acc[j] = __builtin_amdgcn_mfma_f32_16x16x32_bf16(af, bk[j * 64], acc[j], 0, 0, 0);
  }
  #pragma unroll
  for(int j = 0; j < 8; j++){
    int col = j * 16 + lm;
    float bias = rb[v * HIDC + col];
    #pragma unroll
    for(int r = 0; r < 4; r++){
      int row = rowbase + w * 16 + lk * 4 + r;
      if(row < rowlim){
        float hv = acc[j][r] + bias;
        hv = hv > 0.f ? hv : 0.f;
        *(unsigned short*)(A + (size_t)row * RSB + 2048 + col * 2) = f2bf(hv);
      }
    }
  }
}

// GEMM2 + bias + log_softmax -> out (f32)
__global__ __launch_bounds__(256) void gemm2_k(const char* __restrict__ A, const s16x8* __restrict__ Bp,
                                               const float* __restrict__ rb, float* __restrict__ out, int nb0){
  int b = blockIdx.x;
  int v, rowbase, rowlim;
  if(b < nb0){ v = 0; rowbase = b * 64; rowlim = NN0; }
  else       { v = 1; rowbase = NN0 + (b - nb0) * 64; rowlim = NN; }
  int w = threadIdx.x >> 6, l = threadIdx.x & 63;
  int lm = l & 15, lk = l >> 4;
  int mrow = rowbase + w * 16 + lm;
  int mc = mrow < NN ? mrow : NN - 1;
  const char* arow = A + (size_t)mc * RSB;
  const s16x8* bv = Bp + (size_t)v * (KST * 3 * 64);

  f32x4 acc[3];
  #pragma unroll
  for(int j = 0; j < 3; j++) acc[j] = (f32x4)(0.f);

  for(int ks = 0; ks < KST; ks++){
    s16x8 af = *(const s16x8*)(arow + ks * 64 + lk * 16);
    const s16x8* bk = bv + (size_t)ks * (3 * 64) + l;
    #pragma unroll
    for(int j = 0; j < 3; j++)
      acc[j] = __builtin_amdgcn_mfma_f32_16x16x32_bf16(af, bk[j * 64], acc[j], 0, 0, 0);
  }

  float vals[3][4];
  #pragma unroll
  for(int j = 0; j < 3; j++){
    int col = j * 16 + lm;
    float bias = col < OUTC ? rb[v * OUTC + col] : 0.f;
    #pragma unroll
    for(int r = 0; r < 4; r++) vals[j][r] = acc[j][r] + bias;
  }
  float mx[4], se[4];
  #pragma unroll
  for(int r = 0; r < 4; r++){
    float m = -1e30f;
    #pragma unroll
    for(int j = 0; j < 3; j++) if(j * 16 + lm < OUTC) m = fmaxf(m, vals[j][r]);
    mx[r] = m;
  }
  #pragma unroll
  for(int s = 1; s < 16; s <<= 1){
    #pragma unroll
    for(int r = 0; r < 4; r++) mx[r] = fmaxf(mx[r], __shfl_xor(mx[r], s, 64));
  }
  #pragma unroll
  for(int r = 0; r < 4; r++){
    float a = 0.f;
    #pragma unroll
    for(int j = 0; j < 3; j++) if(j * 16 + lm < OUTC) a += __expf(vals[j][r] - mx[r]);
    se[r] = a;
  }
  #pragma unroll
  for(int s = 1; s < 16; s <<= 1){
    #pragma unroll
    for(int r = 0; r < 4; r++) se[r] += __shfl_xor(se[r], s, 64);
  }
  #pragma unroll
  for(int r = 0; r < 4; r++) se[r] = logf(se[r]);
  #pragma unroll
  for(int j = 0; j < 3; j++){
    int col = j * 16 + lm;
    if(col >= OUTC) continue;
    #pragma unroll
    for(int r = 0; r < 4; r++){
      int row = rowbase + w * 16 + lk * 4 + r;
      if(row < rowlim) out[(size_t)row * OUTC + col] = vals[j][r] - mx[r] - se[r];
    }
  }
}

extern "C" void kernel_launch(void* const* d_in, const int* in_sizes, int n_in,
                              void* d_out, int out_size, void* d_ws, size_t ws_size,
                              hipStream_t stream){
  const float* x0  = (const float*)d_in[0];
  const float* e1  = (const float*)d_in[1];
  const float* rw1 = (const float*)d_in[2];
  const float* qw1 = (const float*)d_in[3];
  const float* qb1 = (const float*)d_in[4];
  const float* rw2 = (const float*)d_in[5];
  const float* qw2 = (const float*)d_in[6];
  const float* qb2 = (const float*)d_in[7];
  const int*   ei  = (const int*)d_in[8];
  const int*   et  = (const int*)d_in[9];
  const int*   ntp = (const int*)d_in[10];
  const int*   lix = (const int*)d_in[11];
  float* out = (float*)d_out;

  const size_t A_OFF   = 0;             // 50000*2304 = 115,200,000
  const size_t EB_OFF  = 115200000;     // 50000*64*4 = 12,800,000
  const size_t CNT_OFF = 128000000;     // 1,600,000
  const size_t DEG_OFF = 129600000;     // 200,000
  const size_t OVC_OFF = 129800000;     // 256
  const size_t OVF_OFF = 129800256;     // 262,144
  const size_t INV_OFF = 130062400;     // 1,600,000
  const size_t BP1_OFF = 131662400;     // 589,824
  const size_t BP2_OFF = 132252224;     // 221,184
  const size_t TOTAL   = 132473408;
  if(ws_size < TOTAL) return;

  char* ws = (char*)d_ws;
  char*  A   = ws + A_OFF;
  int*   eb  = (int*)(ws + EB_OFF);
  int*   cnt = (int*)(ws + CNT_OFF);
  int*   deg = (int*)(ws + DEG_OFF);
  int*   ovc = (int*)(ws + OVC_OFF);
  int*   ovf = (int*)(ws + OVF_OFF);
  float* inv = (float*)(ws + INV_OFF);
  short* Bp1 = (short*)(ws + BP1_OFF);
  short* Bp2 = (short*)(ws + BP2_OFF);

  int nb0 = (NN0 + 63) / 64;                    // 469
  int nb1 = (NN - NN0 + 63) / 64;               // 313

  // zero cnt+deg+ovc (contiguous)
  hipMemsetAsync(cnt, 0, 1600000 + 200000 + 256, stream);
  pack1_k<<<(2 * KST * 8 * 64) / 256, 256, 0, stream>>>(rw1, qw1, Bp1);
  pack2_k<<<(2 * KST * 3 * 64 + 255) / 256, 256, 0, stream>>>(rw2, qw2, Bp2);
  xbuild_k<<<(NN * 16 + 255) / 256, 256, 0, stream>>>(x0, e1, ntp, lix, A);
  fill_k<<<(NE + 255) / 256, 256, 0, stream>>>(ei, et, cnt, deg, eb, ovf, ovc);
  inv_k<<<(NN * 8 + 255) / 256, 256, 0, stream>>>(cnt, inv);
  agg_k<<<(NN * 64 + 255) / 256, 256, 0, stream>>>(eb, deg, inv, A, ovf, ovc, ei, et);
  gemm1_k<<<nb0 + nb1, 256, 0, stream>>>(A, (const s16x8*)Bp1, qb1, nb0);
  agg_k<<<(NN * 64 + 255) / 256, 256, 0, stream>>>(eb, deg, inv, A, ovf, ovc, ei, et);
  gemm2_k<<<nb0 + nb1, 256, 0, stream>>>(A, (const s16x8*)Bp2, qb2, out, nb0);
}

// Round 3
// 343.260 us; speedup vs baseline: 6.8575x; 1.0876x over previous
//
#include <hip/hip_runtime.h>

#define NN 50000
#define NN0 30000
#define NN1 20000
#define NE 600000
#define INC 128
#define HIDC 128
#define OUTC 40
#define RS 1152      // A row stride in bf16 elems: 8*128 agg + 128 feat
#define RSB 2304     // row stride bytes
#define KST 36       // K steps of 32 (1152/32)
#define CAP 64       // bucket capacity per dst
#define OVCAP 65536
#define XB 3125      // xbuild blocks (NN*16/256)
#define FB 2344      // fill blocks (ceil(NE/256))

typedef __attribute__((ext_vector_type(4))) float f32x4;
typedef __attribute__((ext_vector_type(8))) short s16x8;

static __device__ __forceinline__ unsigned short f2bf(float f){
  unsigned u = __builtin_bit_cast(unsigned, f);
  u = u + 0x7fffu + ((u >> 16) & 1u);
  return (unsigned short)(u >> 16);
}
static __device__ __forceinline__ float bflo(unsigned w){
  return __builtin_bit_cast(float, w << 16);
}
static __device__ __forceinline__ float bfhi(unsigned w){
  return __builtin_bit_cast(float, w & 0xffff0000u);
}

// fused: blocks [0,XB) gather input features into A tail (bf16);
//        blocks [XB,XB+FB) append edges to per-dst buckets.
__global__ void build_k(const float* __restrict__ x0, const float* __restrict__ e1,
                        const int* __restrict__ ntp, const int* __restrict__ lix,
                        char* __restrict__ A,
                        const int* __restrict__ ei, const int* __restrict__ et,
                        int* __restrict__ deg, int* __restrict__ eb,
                        int* __restrict__ ovf, int* __restrict__ ovc){
  int b = blockIdx.x;
  if(b < XB){
    int tid = b * 256 + threadIdx.x;   // NN*16
    int n = tid >> 4, q = tid & 15;
    if(n >= NN) return;
    int t = ntp[n], li = lix[n];
    const float* s;
    if(t == 0){ li = li < 0 ? 0 : (li > NN0 - 1 ? NN0 - 1 : li); s = x0 + (size_t)li * INC; }
    else      { li = li < 0 ? 0 : (li > NN1 - 1 ? NN1 - 1 : li); s = e1 + (size_t)li * INC; }
    float4 a = ((const float4*)s)[q * 2];
    float4 c = ((const float4*)s)[q * 2 + 1];
    uint4 o;
    o.x = (unsigned)f2bf(a.x) | ((unsigned)f2bf(a.y) << 16);
    o.y = (unsigned)f2bf(a.z) | ((unsigned)f2bf(a.w) << 16);
    o.z = (unsigned)f2bf(c.x) | ((unsigned)f2bf(c.y) << 16);
    o.w = (unsigned)f2bf(c.z) | ((unsigned)f2bf(c.w) << 16);
    *(uint4*)(A + (size_t)n * RSB + 2048 + q * 16) = o;
  } else {
    int e = (b - XB) * 256 + threadIdx.x;
    if(e >= NE) return;
    int s = ei[e], d = ei[NE + e], t = et[e];
    int pos = atomicAdd(&deg[d], 1);
    if(pos < CAP) eb[d * CAP + pos] = s | (t << 16);
    else { int oi = atomicAdd(ovc, 1); if(oi < OVCAP) ovf[oi] = e; }
  }
}

// one wave per dst: scan bucket (wave-uniform broadcast entries), accumulate
// per-type channel sums in regs, count per-type edges in SGPRs, scale, store.
__global__ __launch_bounds__(256) void agg_k(const int* __restrict__ eb, const int* __restrict__ deg,
                                             char* __restrict__ A,
                                             const int* __restrict__ ovf, const int* __restrict__ ovc,
                                             const int* __restrict__ ei, const int* __restrict__ et){
  int wid = (blockIdx.x * 256 + threadIdx.x) >> 6;
  int l = threadIdx.x & 63;
  if(wid >= NN) return;
  int d = wid;
  int dg = deg[d];
  int nb = dg < CAP ? dg : CAP;
  int ent = eb[d * CAP + l];   // lane l holds bucket entry l (coalesced)
  const char* Af = A + 2048;
  float acc[16];
  #pragma unroll
  for(int j = 0; j < 16; j++) acc[j] = 0.f;
  int c0 = 0, c1 = 0, c2 = 0, c3 = 0, c4 = 0, c5 = 0, c6 = 0, c7 = 0;

#define ACCUM(T, FX, FY) \
  switch(T){ \
    case 0: acc[0]  += FX; acc[1]  += FY; c0++; break; \
    case 1: acc[2]  += FX; acc[3]  += FY; c1++; break; \
    case 2: acc[4]  += FX; acc[5]  += FY; c2++; break; \
    case 3: acc[6]  += FX; acc[7]  += FY; c3++; break; \
    case 4: acc[8]  += FX; acc[9]  += FY; c4++; break; \
    case 5: acc[10] += FX; acc[11] += FY; c5++; break; \
    case 6: acc[12] += FX; acc[13] += FY; c6++; break; \
    default: acc[14] += FX; acc[15] += FY; c7++; break; \
  }

  int i = 0;
  for(; i + 1 < nb; i += 2){
    int p0 = __shfl(ent, i, 64);
    int p1 = __shfl(ent, i + 1, 64);
    unsigned w0 = *(const unsigned*)(Af + (size_t)(p0 & 0xffff) * RSB + l * 4);
    unsigned w1 = *(const unsigned*)(Af + (size_t)(p1 & 0xffff) * RSB + l * 4);
    int t0 = __builtin_amdgcn_readfirstlane(p0) >> 16;
    int t1 = __builtin_amdgcn_readfirstlane(p1) >> 16;
    float fx0 = bflo(w0), fy0 = bfhi(w0);
    float fx1 = bflo(w1), fy1 = bfhi(w1);
    ACCUM(t0, fx0, fy0);
    ACCUM(t1, fx1, fy1);
  }
  if(i < nb){
    int p0 = __shfl(ent, i, 64);
    unsigned w0 = *(const unsigned*)(Af + (size_t)(p0 & 0xffff) * RSB + l * 4);
    int t0 = __builtin_amdgcn_readfirstlane(p0) >> 16;
    float fx0 = bflo(w0), fy0 = bfhi(w0);
    ACCUM(t0, fx0, fy0);
  }
  if(dg > CAP){
    int oc = *ovc; if(oc > OVCAP) oc = OVCAP;
    for(int k = 0; k < oc; k++){
      int e = ovf[k];
      if(ei[NE + e] != d) continue;
      int s = ei[e];
      int t0 = et[e];
      unsigned w0 = *(const unsigned*)(Af + (size_t)s * RSB + l * 4);
      float fx0 = bflo(w0), fy0 = bfhi(w0);
      ACCUM(t0, fx0, fy0);
    }
  }
#undef ACCUM

#define STORE(TT, CT) { \
    float iv = 1.0f / (float)((CT) > 1 ? (CT) : 1); \
    unsigned o = (unsigned)f2bf(acc[2*(TT)] * iv) | ((unsigned)f2bf(acc[2*(TT)+1] * iv) << 16); \
    *(unsigned*)(A + (size_t)d * RSB + (TT) * 256 + l * 4) = o; \
  }
  STORE(0, c0); STORE(1, c1); STORE(2, c2); STORE(3, c3);
  STORE(4, c4); STORE(5, c5); STORE(6, c6); STORE(7, c7);
#undef STORE
}

// pack B1 and B2 in one grid.
// B1: [v][ks][j(8)][lane(64)][8] bf16 ; B[k][n] = W[n][k]; k>=1024 -> root_w[v]
// B2: [v][ks][j(3)][lane(64)][8] bf16 ; cols >= 40 zero
__global__ void pack_k(const float* __restrict__ rw1, const float* __restrict__ qw1,
                       const float* __restrict__ rw2, const float* __restrict__ qw2,
                       short* __restrict__ Bp1, short* __restrict__ Bp2){
  int tid = blockIdx.x * 256 + threadIdx.x;
  if(tid < 2 * KST * 8 * 64){
    int l = tid & 63, j = (tid >> 6) & 7, ks = (tid >> 9) % KST, v = (tid >> 9) / KST;
    int n = j * 16 + (l & 15);
    int kb = ks * 32 + (l >> 4) * 8;
    s16x8 ov;
    #pragma unroll
    for(int jj = 0; jj < 8; jj++){
      int k = kb + jj; float wv;
      if(k < 1024){ int t = k >> 7, ki = k & 127; wv = rw1[((size_t)t * HIDC + n) * INC + ki]; }
      else        { wv = qw1[((size_t)v * HIDC + n) * INC + (k - 1024)]; }
      ov[jj] = (short)f2bf(wv);
    }
    ((s16x8*)Bp1)[tid] = ov;
    return;
  }
  int tid2 = tid - 2 * KST * 8 * 64;
  if(tid2 >= 2 * KST * 3 * 64) return;
  int l = tid2 & 63;
  int q = tid2 >> 6;
  int j = q % 3; q /= 3;
  int ks = q % KST, v = q / KST;
  int n = j * 16 + (l & 15);
  int kb = ks * 32 + (l >> 4) * 8;
  s16x8 ov;
  #pragma unroll
  for(int jj = 0; jj < 8; jj++){
    int k = kb + jj; float wv = 0.f;
    if(n < OUTC){
      if(k < 1024){ int t = k >> 7, ki = k & 127; wv = rw2[((size_t)t * OUTC + n) * INC + ki]; }
      else        { wv = qw2[((size_t)v * OUTC + n) * INC + (k - 1024)]; }
    }
    ov[jj] = (short)f2bf(wv);
  }
  ((s16x8*)Bp2)[tid2] = ov;
}

// GEMM1: h = relu(A @ B1^T + b1) written into A tail (bf16). 64 rows/block, 4 waves.
__global__ __launch_bounds__(256) void gemm1_k(char* __restrict__ A, const s16x8* __restrict__ Bp,
                                               const float* __restrict__ rb, int nb0){
  int b = blockIdx.x;
  int v, rowbase, rowlim;
  if(b < nb0){ v = 0; rowbase = b * 64; rowlim = NN0; }
  else       { v = 1; rowbase = NN0 + (b - nb0) * 64; rowlim = NN; }
  int w = threadIdx.x >> 6, l = threadIdx.x & 63;
  int lm = l & 15, lk = l >> 4;
  int mrow = rowbase + w * 16 + lm;
  int mc = mrow < NN ? mrow : NN - 1;
  const char* arow = A + (size_t)mc * RSB;
  const s16x8* bv = Bp + (size_t)v * (KST * 8 * 64);

  f32x4 acc[8];
  #pragma unroll
  for(int j = 0; j < 8; j++) acc[j] = (f32x4)(0.f);

  for(int ks = 0; ks < KST; ks++){
    s16x8 af = *(const s16x8*)(arow + ks * 64 + lk * 16);
    const s16x8* bk = bv + (size_t)ks * (8 * 64) + l;
    #pragma unroll
    for(int j = 0; j < 8; j++)
      acc[j] = __builtin_amdgcn_mfma_f32_16x16x32_bf16(af, bk[j * 64], acc[j], 0, 0, 0);
  }
  #pragma unroll
  for(int j = 0; j < 8; j++){
    int col = j * 16 + lm;
    float bias = rb[v * HIDC + col];
    #pragma unroll
    for(int r = 0; r < 4; r++){
      int row = rowbase + w * 16 + lk * 4 + r;
      if(row < rowlim){
        float hv = acc[j][r] + bias;
        hv = hv > 0.f ? hv : 0.f;
        *(unsigned short*)(A + (size_t)row * RSB + 2048 + col * 2) = f2bf(hv);
      }
    }
  }
}

// GEMM2 + bias + log_softmax -> out (f32)
__global__ __launch_bounds__(256) void gemm2_k(const char* __restrict__ A, const s16x8* __restrict__ Bp,
                                               const float* __restrict__ rb, float* __restrict__ out, int nb0){
  int b = blockIdx.x;
  int v, rowbase, rowlim;
  if(b < nb0){ v = 0; rowbase = b * 64; rowlim = NN0; }
  else       { v = 1; rowbase = NN0 + (b - nb0) * 64; rowlim = NN; }
  int w = threadIdx.x >> 6, l = threadIdx.x & 63;
  int lm = l & 15, lk = l >> 4;
  int mrow = rowbase + w * 16 + lm;
  int mc = mrow < NN ? mrow : NN - 1;
  const char* arow = A + (size_t)mc * RSB;
  const s16x8* bv = Bp + (size_t)v * (KST * 3 * 64);

  f32x4 acc[3];
  #pragma unroll
  for(int j = 0; j < 3; j++) acc[j] = (f32x4)(0.f);

  for(int ks = 0; ks < KST; ks++){
    s16x8 af = *(const s16x8*)(arow + ks * 64 + lk * 16);
    const s16x8* bk = bv + (size_t)ks * (3 * 64) + l;
    #pragma unroll
    for(int j = 0; j < 3; j++)
      acc[j] = __builtin_amdgcn_mfma_f32_16x16x32_bf16(af, bk[j * 64], acc[j], 0, 0, 0);
  }

  float vals[3][4];
  #pragma unroll
  for(int j = 0; j < 3; j++){
    int col = j * 16 + lm;
    float bias = col < OUTC ? rb[v * OUTC + col] : 0.f;
    #pragma unroll
    for(int r = 0; r < 4; r++) vals[j][r] = acc[j][r] + bias;
  }
  float mx[4], se[4];
  #pragma unroll
  for(int r = 0; r < 4; r++){
    float m = -1e30f;
    #pragma unroll
    for(int j = 0; j < 3; j++) if(j * 16 + lm < OUTC) m = fmaxf(m, vals[j][r]);
    mx[r] = m;
  }
  #pragma unroll
  for(int s = 1; s < 16; s <<= 1){
    #pragma unroll
    for(int r = 0; r < 4; r++) mx[r] = fmaxf(mx[r], __shfl_xor(mx[r], s, 64));
  }
  #pragma unroll
  for(int r = 0; r < 4; r++){
    float a = 0.f;
    #pragma unroll
    for(int j = 0; j < 3; j++) if(j * 16 + lm < OUTC) a += __expf(vals[j][r] - mx[r]);
    se[r] = a;
  }
  #pragma unroll
  for(int s = 1; s < 16; s <<= 1){
    #pragma unroll
    for(int r = 0; r < 4; r++) se[r] += __shfl_xor(se[r], s, 64);
  }
  #pragma unroll
  for(int r = 0; r < 4; r++) se[r] = logf(se[r]);
  #pragma unroll
  for(int j = 0; j < 3; j++){
    int col = j * 16 + lm;
    if(col >= OUTC) continue;
    #pragma unroll
    for(int r = 0; r < 4; r++){
      int row = rowbase + w * 16 + lk * 4 + r;
      if(row < rowlim) out[(size_t)row * OUTC + col] = vals[j][r] - mx[r] - se[r];
    }
  }
}

extern "C" void kernel_launch(void* const* d_in, const int* in_sizes, int n_in,
                              void* d_out, int out_size, void* d_ws, size_t ws_size,
                              hipStream_t stream){
  const float* x0  = (const float*)d_in[0];
  const float* e1  = (const float*)d_in[1];
  const float* rw1 = (const float*)d_in[2];
  const float* qw1 = (const float*)d_in[3];
  const float* qb1 = (const float*)d_in[4];
  const float* rw2 = (const float*)d_in[5];
  const float* qw2 = (const float*)d_in[6];
  const float* qb2 = (const float*)d_in[7];
  const int*   ei  = (const int*)d_in[8];
  const int*   et  = (const int*)d_in[9];
  const int*   ntp = (const int*)d_in[10];
  const int*   lix = (const int*)d_in[11];
  float* out = (float*)d_out;

  const size_t A_OFF   = 0;             // 50000*2304 = 115,200,000
  const size_t EB_OFF  = 115200000;     // 50000*64*4 = 12,800,000
  const size_t DEG_OFF = 128000000;     // 200,000
  const size_t OVC_OFF = 128200000;     // 256
  const size_t OVF_OFF = 128200256;     // 262,144
  const size_t BP1_OFF = 128462400;     // 589,824
  const size_t BP2_OFF = 129052224;     // 221,184
  const size_t TOTAL   = 129273408;
  if(ws_size < TOTAL) return;

  char* ws = (char*)d_ws;
  char*  A   = ws + A_OFF;
  int*   eb  = (int*)(ws + EB_OFF);
  int*   deg = (int*)(ws + DEG_OFF);
  int*   ovc = (int*)(ws + OVC_OFF);
  int*   ovf = (int*)(ws + OVF_OFF);
  short* Bp1 = (short*)(ws + BP1_OFF);
  short* Bp2 = (short*)(ws + BP2_OFF);

  int nb0 = (NN0 + 63) / 64;                    // 469
  int nb1 = (NN - NN0 + 63) / 64;               // 313

  hipMemsetAsync(deg, 0, 200000 + 256, stream);           // deg + ovc (adjacent)
  pack_k<<<(2 * KST * 8 * 64 + 2 * KST * 3 * 64 + 255) / 256, 256, 0, stream>>>(rw1, qw1, rw2, qw2, Bp1, Bp2);
  build_k<<<XB + FB, 256, 0, stream>>>(x0, e1, ntp, lix, A, ei, et, deg, eb, ovf, ovc);
  agg_k<<<(NN * 64 + 255) / 256, 256, 0, stream>>>(eb, deg, A, ovf, ovc, ei, et);
  gemm1_k<<<nb0 + nb1, 256, 0, stream>>>(A, (const s16x8*)Bp1, qb1, nb0);
  agg_k<<<(NN * 64 + 255) / 256, 256, 0, stream>>>(eb, deg, A, ovf, ovc, ei, et);
  gemm2_k<<<nb0 + nb1, 256, 0, stream>>>(A, (const s16x8*)Bp2, qb2, out, nb0);
}

// Round 4
// 330.093 us; speedup vs baseline: 7.1310x; 1.0399x over previous
//
#include <hip/hip_runtime.h>

#define NN 50000
#define NN0 30000
#define NN1 20000
#define NE 600000
#define INC 128
#define HIDC 128
#define OUTC 40
#define RS 1152      // A row stride in bf16 elems: 8*128 agg + 128 feat
#define RSB 2304     // row stride bytes
#define KST 36       // K steps of 32 (1152/32)
#define CAP 64       // bucket capacity per dst
#define OVCAP 65536
#define XB 3125      // xbuild blocks (NN*16/256)
#define FB 2344      // fill blocks (ceil(NE/256))
#define PB 198       // pack blocks ((2*36*8*64 + 2*36*3*64)/256)

typedef __attribute__((ext_vector_type(4))) float f32x4;
typedef __attribute__((ext_vector_type(8))) short s16x8;

static __device__ __forceinline__ unsigned short f2bf(float f){
  unsigned u = __builtin_bit_cast(unsigned, f);
  u = u + 0x7fffu + ((u >> 16) & 1u);
  return (unsigned short)(u >> 16);
}
static __device__ __forceinline__ float bflo(unsigned w){
  return __builtin_bit_cast(float, w << 16);
}
static __device__ __forceinline__ float bfhi(unsigned w){
  return __builtin_bit_cast(float, w & 0xffff0000u);
}

// fused grid: [0,XB) gather features -> A tail; [XB,XB+FB) bucket edges;
//             [XB+FB,XB+FB+PB) pack B1/B2.
__global__ void build_k(const float* __restrict__ x0, const float* __restrict__ e1,
                        const int* __restrict__ ntp, const int* __restrict__ lix,
                        char* __restrict__ A,
                        const int* __restrict__ ei, const int* __restrict__ et,
                        int* __restrict__ deg, int* __restrict__ eb,
                        int* __restrict__ ovf, int* __restrict__ ovc,
                        const float* __restrict__ rw1, const float* __restrict__ qw1,
                        const float* __restrict__ rw2, const float* __restrict__ qw2,
                        short* __restrict__ Bp1, short* __restrict__ Bp2){
  int b = blockIdx.x;
  if(b < XB){
    int tid = b * 256 + threadIdx.x;   // NN*16
    int n = tid >> 4, q = tid & 15;
    if(n >= NN) return;
    int t = ntp[n], li = lix[n];
    const float* s;
    if(t == 0){ li = li < 0 ? 0 : (li > NN0 - 1 ? NN0 - 1 : li); s = x0 + (size_t)li * INC; }
    else      { li = li < 0 ? 0 : (li > NN1 - 1 ? NN1 - 1 : li); s = e1 + (size_t)li * INC; }
    float4 a = ((const float4*)s)[q * 2];
    float4 c = ((const float4*)s)[q * 2 + 1];
    uint4 o;
    o.x = (unsigned)f2bf(a.x) | ((unsigned)f2bf(a.y) << 16);
    o.y = (unsigned)f2bf(a.z) | ((unsigned)f2bf(a.w) << 16);
    o.z = (unsigned)f2bf(c.x) | ((unsigned)f2bf(c.y) << 16);
    o.w = (unsigned)f2bf(c.z) | ((unsigned)f2bf(c.w) << 16);
    *(uint4*)(A + (size_t)n * RSB + 2048 + q * 16) = o;
    return;
  }
  if(b < XB + FB){
    int e = (b - XB) * 256 + threadIdx.x;
    if(e >= NE) return;
    int s = ei[e], d = ei[NE + e], t = et[e];
    int pos = atomicAdd(&deg[d], 1);
    if(pos < CAP) eb[d * CAP + pos] = s | (t << 16);
    else { int oi = atomicAdd(ovc, 1); if(oi < OVCAP) ovf[oi] = e; }
    return;
  }
  int tid = (b - XB - FB) * 256 + threadIdx.x;
  if(tid < 2 * KST * 8 * 64){
    int l = tid & 63, j = (tid >> 6) & 7, ks = (tid >> 9) % KST, v = (tid >> 9) / KST;
    int n = j * 16 + (l & 15);
    int kb = ks * 32 + (l >> 4) * 8;
    s16x8 ov;
    #pragma unroll
    for(int jj = 0; jj < 8; jj++){
      int k = kb + jj; float wv;
      if(k < 1024){ int t = k >> 7, ki = k & 127; wv = rw1[((size_t)t * HIDC + n) * INC + ki]; }
      else        { wv = qw1[((size_t)v * HIDC + n) * INC + (k - 1024)]; }
      ov[jj] = (short)f2bf(wv);
    }
    ((s16x8*)Bp1)[tid] = ov;
    return;
  }
  int tid2 = tid - 2 * KST * 8 * 64;
  if(tid2 >= 2 * KST * 3 * 64) return;
  int l = tid2 & 63;
  int q = tid2 >> 6;
  int j = q % 3; q /= 3;
  int ks = q % KST, v = q / KST;
  int n = j * 16 + (l & 15);
  int kb = ks * 32 + (l >> 4) * 8;
  s16x8 ov;
  #pragma unroll
  for(int jj = 0; jj < 8; jj++){
    int k = kb + jj; float wv = 0.f;
    if(n < OUTC){
      if(k < 1024){ int t = k >> 7, ki = k & 127; wv = rw2[((size_t)t * OUTC + n) * INC + ki]; }
      else        { wv = qw2[((size_t)v * OUTC + n) * INC + (k - 1024)]; }
    }
    ov[jj] = (short)f2bf(wv);
  }
  ((s16x8*)Bp2)[tid2] = ov;
}

// one wave per dst. Wave-uniform bucket scan: entries come in via SCALAR loads
// (d made uniform with readfirstlane), source-row base lives in SGPRs, the
// per-lane load is saddr + lane*4. Type dispatch = uniform SALU switch.
__global__ __launch_bounds__(256) void agg_k(const int* __restrict__ eb, const int* __restrict__ deg,
                                             char* __restrict__ A,
                                             const int* __restrict__ ovf, const int* __restrict__ ovc,
                                             const int* __restrict__ ei, const int* __restrict__ et){
  int wid = (blockIdx.x * 256 + threadIdx.x) >> 6;
  int l = threadIdx.x & 63;
  if(wid >= NN) return;
  int d = __builtin_amdgcn_readfirstlane(wid);
  int dg = deg[d];
  int nb = dg < CAP ? dg : CAP;
  const char* Af = A + 2048;
  int voff = l * 4;
  float acc[16];
  #pragma unroll
  for(int j = 0; j < 16; j++) acc[j] = 0.f;
  int c0 = 0, c1 = 0, c2 = 0, c3 = 0, c4 = 0, c5 = 0, c6 = 0, c7 = 0;

#define ACCUM(T, W) { \
  float fx_ = bflo(W), fy_ = bfhi(W); \
  switch(T){ \
    case 0: acc[0]  += fx_; acc[1]  += fy_; c0++; break; \
    case 1: acc[2]  += fx_; acc[3]  += fy_; c1++; break; \
    case 2: acc[4]  += fx_; acc[5]  += fy_; c2++; break; \
    case 3: acc[6]  += fx_; acc[7]  += fy_; c3++; break; \
    case 4: acc[8]  += fx_; acc[9]  += fy_; c4++; break; \
    case 5: acc[10] += fx_; acc[11] += fy_; c5++; break; \
    case 6: acc[12] += fx_; acc[13] += fy_; c6++; break; \
    default: acc[14] += fx_; acc[15] += fy_; c7++; break; \
  } }

  int base = d * CAP;
  int i = 0;
  for(; i + 3 < nb; i += 4){
    int p0 = eb[base + i + 0];
    int p1 = eb[base + i + 1];
    int p2 = eb[base + i + 2];
    int p3 = eb[base + i + 3];
    unsigned w0 = *(const unsigned*)(Af + (size_t)(p0 & 0xffff) * RSB + voff);
    unsigned w1 = *(const unsigned*)(Af + (size_t)(p1 & 0xffff) * RSB + voff);
    unsigned w2 = *(const unsigned*)(Af + (size_t)(p2 & 0xffff) * RSB + voff);
    unsigned w3 = *(const unsigned*)(Af + (size_t)(p3 & 0xffff) * RSB + voff);
    ACCUM(p0 >> 16, w0);
    ACCUM(p1 >> 16, w1);
    ACCUM(p2 >> 16, w2);
    ACCUM(p3 >> 16, w3);
  }
  for(; i < nb; i++){
    int p0 = eb[base + i];
    unsigned w0 = *(const unsigned*)(Af + (size_t)(p0 & 0xffff) * RSB + voff);
    ACCUM(p0 >> 16, w0);
  }
  if(dg > CAP){
    int oc = *ovc; if(oc > OVCAP) oc = OVCAP;
    for(int k = 0; k < oc; k++){
      int e = ovf[k];
      if(ei[NE + e] != d) continue;
      int s = ei[e];
      int t0 = et[e];
      unsigned w0 = *(const unsigned*)(Af + (size_t)s * RSB + voff);
      ACCUM(t0, w0);
    }
  }
#undef ACCUM

#define STORE(TT, CT) { \
    float iv = 1.0f / (float)((CT) > 1 ? (CT) : 1); \
    unsigned o = (unsigned)f2bf(acc[2*(TT)] * iv) | ((unsigned)f2bf(acc[2*(TT)+1] * iv) << 16); \
    *(unsigned*)(A + (size_t)d * RSB + (TT) * 256 + voff) = o; \
  }
  STORE(0, c0); STORE(1, c1); STORE(2, c2); STORE(3, c3);
  STORE(4, c4); STORE(5, c5); STORE(6, c6); STORE(7, c7);
#undef STORE
}

// GEMM1: h = relu(A @ B1^T + b1) written into A tail (bf16). 64 rows/block, 4 waves.
__global__ __launch_bounds__(256) void gemm1_k(char* __restrict__ A, const s16x8* __restrict__ Bp,
                                               const float* __restrict__ rb, int nb0){
  int b = blockIdx.x;
  int v, rowbase, rowlim;
  if(b < nb0){ v = 0; rowbase = b * 64; rowlim = NN0; }
  else       { v = 1; rowbase = NN0 + (b - nb0) * 64; rowlim = NN; }
  int w = threadIdx.x >> 6, l = threadIdx.x & 63;
  int lm = l & 15, lk = l >> 4;
  int mrow = rowbase + w * 16 + lm;
  int mc = mrow < NN ? mrow : NN - 1;
  const char* arow = A + (size_t)mc * RSB;
  const s16x8* bv = Bp + (size_t)v * (KST * 8 * 64);

  f32x4 acc[8];
  #pragma unroll
  for(int j = 0; j < 8; j++) acc[j] = (f32x4)(0.f);

  for(int ks = 0; ks < KST; ks++){
    s16x8 af = *(const s16x8*)(arow + ks * 64 + lk * 16);
    const s16x8* bk = bv + (size_t)ks * (8 * 64) + l;
    #pragma unroll
    for(int j = 0; j < 8; j++)
      acc[j] = __builtin_amdgcn_mfma_f32_16x16x32_bf16(af, bk[j * 64], acc[j], 0, 0, 0);
  }
  #pragma unroll
  for(int j = 0; j < 8; j++){
    int col = j * 16 + lm;
    float bias = rb[v * HIDC + col];
    #pragma unroll
    for(int r = 0; r < 4; r++){
      int row = rowbase + w * 16 + lk * 4 + r;
      if(row < rowlim){
        float hv = acc[j][r] + bias;
        hv = hv > 0.f ? hv : 0.f;
        *(unsigned short*)(A + (size_t)row * RSB + 2048 + col * 2) = f2bf(hv);
      }
    }
  }
}

// GEMM2 + bias + log_softmax -> out (f32)
__global__ __launch_bounds__(256) void gemm2_k(const char* __restrict__ A, const s16x8* __restrict__ Bp,
                                               const float* __restrict__ rb, float* __restrict__ out, int nb0){
  int b = blockIdx.x;
  int v, rowbase, rowlim;
  if(b < nb0){ v = 0; rowbase = b * 64; rowlim = NN0; }
  else       { v = 1; rowbase = NN0 + (b - nb0) * 64; rowlim = NN; }
  int w = threadIdx.x >> 6, l = threadIdx.x & 63;
  int lm = l & 15, lk = l >> 4;
  int mrow = rowbase + w * 16 + lm;
  int mc = mrow < NN ? mrow : NN - 1;
  const char* arow = A + (size_t)mc * RSB;
  const s16x8* bv = Bp + (size_t)v * (KST * 3 * 64);

  f32x4 acc[3];
  #pragma unroll
  for(int j = 0; j < 3; j++) acc[j] = (f32x4)(0.f);

  for(int ks = 0; ks < KST; ks++){
    s16x8 af = *(const s16x8*)(arow + ks * 64 + lk * 16);
    const s16x8* bk = bv + (size_t)ks * (3 * 64) + l;
    #pragma unroll
    for(int j = 0; j < 3; j++)
      acc[j] = __builtin_amdgcn_mfma_f32_16x16x32_bf16(af, bk[j * 64], acc[j], 0, 0, 0);
  }

  float vals[3][4];
  #pragma unroll
  for(int j = 0; j < 3; j++){
    int col = j * 16 + lm;
    float bias = col < OUTC ? rb[v * OUTC + col] : 0.f;
    #pragma unroll
    for(int r = 0; r < 4; r++) vals[j][r] = acc[j][r] + bias;
  }
  float mx[4], se[4];
  #pragma unroll
  for(int r = 0; r < 4; r++){
    float m = -1e30f;
    #pragma unroll
    for(int j = 0; j < 3; j++) if(j * 16 + lm < OUTC) m = fmaxf(m, vals[j][r]);
    mx[r] = m;
  }
  #pragma unroll
  for(int s = 1; s < 16; s <<= 1){
    #pragma unroll
    for(int r = 0; r < 4; r++) mx[r] = fmaxf(mx[r], __shfl_xor(mx[r], s, 64));
  }
  #pragma unroll
  for(int r = 0; r < 4; r++){
    float a = 0.f;
    #pragma unroll
    for(int j = 0; j < 3; j++) if(j * 16 + lm < OUTC) a += __expf(vals[j][r] - mx[r]);
    se[r] = a;
  }
  #pragma unroll
  for(int s = 1; s < 16; s <<= 1){
    #pragma unroll
    for(int r = 0; r < 4; r++) se[r] += __shfl_xor(se[r], s, 64);
  }
  #pragma unroll
  for(int r = 0; r < 4; r++) se[r] = logf(se[r]);
  #pragma unroll
  for(int j = 0; j < 3; j++){
    int col = j * 16 + lm;
    if(col >= OUTC) continue;
    #pragma unroll
    for(int r = 0; r < 4; r++){
      int row = rowbase + w * 16 + lk * 4 + r;
      if(row < rowlim) out[(size_t)row * OUTC + col] = vals[j][r] - mx[r] - se[r];
    }
  }
}

extern "C" void kernel_launch(void* const* d_in, const int* in_sizes, int n_in,
                              void* d_out, int out_size, void* d_ws, size_t ws_size,
                              hipStream_t stream){
  const float* x0  = (const float*)d_in[0];
  const float* e1  = (const float*)d_in[1];
  const float* rw1 = (const float*)d_in[2];
  const float* qw1 = (const float*)d_in[3];
  const float* qb1 = (const float*)d_in[4];
  const float* rw2 = (const float*)d_in[5];
  const float* qw2 = (const float*)d_in[6];
  const float* qb2 = (const float*)d_in[7];
  const int*   ei  = (const int*)d_in[8];
  const int*   et  = (const int*)d_in[9];
  const int*   ntp = (const int*)d_in[10];
  const int*   lix = (const int*)d_in[11];
  float* out = (float*)d_out;

  const size_t A_OFF   = 0;             // 50000*2304 = 115,200,000
  const size_t EB_OFF  = 115200000;     // 50000*64*4 = 12,800,000
  const size_t DEG_OFF = 128000000;     // 200,000
  const size_t OVC_OFF = 128200000;     // 256
  const size_t OVF_OFF = 128200256;     // 262,144
  const size_t BP1_OFF = 128462400;     // 589,824
  const size_t BP2_OFF = 129052224;     // 221,184
  const size_t TOTAL   = 129273408;
  if(ws_size < TOTAL) return;

  char* ws = (char*)d_ws;
  char*  A   = ws + A_OFF;
  int*   eb  = (int*)(ws + EB_OFF);
  int*   deg = (int*)(ws + DEG_OFF);
  int*   ovc = (int*)(ws + OVC_OFF);
  int*   ovf = (int*)(ws + OVF_OFF);
  short* Bp1 = (short*)(ws + BP1_OFF);
  short* Bp2 = (short*)(ws + BP2_OFF);

  int nb0 = (NN0 + 63) / 64;                    // 469
  int nb1 = (NN - NN0 + 63) / 64;               // 313

  hipMemsetAsync(deg, 0, 200000 + 256, stream);           // deg + ovc (adjacent)
  build_k<<<XB + FB + PB, 256, 0, stream>>>(x0, e1, ntp, lix, A, ei, et, deg, eb, ovf, ovc,
                                            rw1, qw1, rw2, qw2, Bp1, Bp2);
  agg_k<<<(NN * 64 + 255) / 256, 256, 0, stream>>>(eb, deg, A, ovf, ovc, ei, et);
  gemm1_k<<<nb0 + nb1, 256, 0, stream>>>(A, (const s16x8*)Bp1, qb1, nb0);
  agg_k<<<(NN * 64 + 255) / 256, 256, 0, stream>>>(eb, deg, A, ovf, ovc, ei, et);
  gemm2_k<<<nb0 + nb1, 256, 0, stream>>>(A, (const s16x8*)Bp2, qb2, out, nb0);
}

// Round 6
// 328.099 us; speedup vs baseline: 7.1743x; 1.0061x over previous
//
#include <hip/hip_runtime.h>

#define NN 50000
#define NN0 30000
#define NN1 20000
#define NE 600000
#define INC 128
#define HIDC 128
#define OUTC 40
#define RS 1152      // A row stride in bf16 elems: 8*128 agg + 128 feat
#define RSB 2304     // row stride bytes
#define KST 36       // K steps of 32 (1152/32)
#define CAP 64       // bucket capacity per dst
#define OVCAP 65536
#define XB 3125      // xbuild blocks (NN*16/256)
#define FB 2344      // fill blocks (ceil(NE/256))
#define PB 198       // pack blocks ((2*36*8*64 + 2*36*3*64)/256)

typedef __attribute__((ext_vector_type(4))) float f32x4;
typedef __attribute__((ext_vector_type(8))) short s16x8;

static __device__ __forceinline__ unsigned short f2bf(float f){
  unsigned u = __builtin_bit_cast(unsigned, f);
  u = u + 0x7fffu + ((u >> 16) & 1u);
  return (unsigned short)(u >> 16);
}
static __device__ __forceinline__ float bflo(unsigned w){
  return __builtin_bit_cast(float, w << 16);
}
static __device__ __forceinline__ float bfhi(unsigned w){
  return __builtin_bit_cast(float, w & 0xffff0000u);
}

// fused grid: [0,XB) gather features -> A tail; [XB,XB+FB) bucket edges;
//             [XB+FB,XB+FB+PB) pack B1/B2.
__global__ void build_k(const float* __restrict__ x0, const float* __restrict__ e1,
                        const int* __restrict__ ntp, const int* __restrict__ lix,
                        char* __restrict__ A,
                        const int* __restrict__ ei, const int* __restrict__ et,
                        int* __restrict__ deg, int* __restrict__ eb,
                        int* __restrict__ ovf, int* __restrict__ ovc,
                        const float* __restrict__ rw1, const float* __restrict__ qw1,
                        const float* __restrict__ rw2, const float* __restrict__ qw2,
                        short* __restrict__ Bp1, short* __restrict__ Bp2){
  int b = blockIdx.x;
  if(b < XB){
    int tid = b * 256 + threadIdx.x;   // NN*16
    int n = tid >> 4, q = tid & 15;
    if(n >= NN) return;
    int t = ntp[n], li = lix[n];
    const float* s;
    if(t == 0){ li = li < 0 ? 0 : (li > NN0 - 1 ? NN0 - 1 : li); s = x0 + (size_t)li * INC; }
    else      { li = li < 0 ? 0 : (li > NN1 - 1 ? NN1 - 1 : li); s = e1 + (size_t)li * INC; }
    float4 a = ((const float4*)s)[q * 2];
    float4 c = ((const float4*)s)[q * 2 + 1];
    uint4 o;
    o.x = (unsigned)f2bf(a.x) | ((unsigned)f2bf(a.y) << 16);
    o.y = (unsigned)f2bf(a.z) | ((unsigned)f2bf(a.w) << 16);
    o.z = (unsigned)f2bf(c.x) | ((unsigned)f2bf(c.y) << 16);
    o.w = (unsigned)f2bf(c.z) | ((unsigned)f2bf(c.w) << 16);
    *(uint4*)(A + (size_t)n * RSB + 2048 + q * 16) = o;
    return;
  }
  if(b < XB + FB){
    int e = (b - XB) * 256 + threadIdx.x;
    if(e >= NE) return;
    int s = ei[e], d = ei[NE + e], t = et[e];
    int pos = atomicAdd(&deg[d], 1);
    if(pos < CAP) eb[d * CAP + pos] = s | (t << 16);
    else { int oi = atomicAdd(ovc, 1); if(oi < OVCAP) ovf[oi] = e; }
    return;
  }
  int tid = (b - XB - FB) * 256 + threadIdx.x;
  if(tid < 2 * KST * 8 * 64){
    int l = tid & 63, j = (tid >> 6) & 7, ks = (tid >> 9) % KST, v = (tid >> 9) / KST;
    int n = j * 16 + (l & 15);
    int kb = ks * 32 + (l >> 4) * 8;
    s16x8 ov;
    #pragma unroll
    for(int jj = 0; jj < 8; jj++){
      int k = kb + jj; float wv;
      if(k < 1024){ int t = k >> 7, ki = k & 127; wv = rw1[((size_t)t * HIDC + n) * INC + ki]; }
      else        { wv = qw1[((size_t)v * HIDC + n) * INC + (k - 1024)]; }
      ov[jj] = (short)f2bf(wv);
    }
    ((s16x8*)Bp1)[tid] = ov;
    return;
  }
  int tid2 = tid - 2 * KST * 8 * 64;
  if(tid2 >= 2 * KST * 3 * 64) return;
  int l = tid2 & 63;
  int q = tid2 >> 6;
  int j = q % 3; q /= 3;
  int ks = q % KST, v = q / KST;
  int n = j * 16 + (l & 15);
  int kb = ks * 32 + (l >> 4) * 8;
  s16x8 ov;
  #pragma unroll
  for(int jj = 0; jj < 8; jj++){
    int k = kb + jj; float wv = 0.f;
    if(n < OUTC){
      if(k < 1024){ int t = k >> 7, ki = k & 127; wv = rw2[((size_t)t * OUTC + n) * INC + ki]; }
      else        { wv = qw2[((size_t)v * OUTC + n) * INC + (k - 1024)]; }
    }
    ov[jj] = (short)f2bf(wv);
  }
  ((s16x8*)Bp2)[tid2] = ov;
}

// one wave per dst. Wave-uniform bucket scan: entries via scalar loads,
// source-row base in SGPRs, per-lane load = saddr + lane*4.
__global__ __launch_bounds__(256) void agg_k(const int* __restrict__ eb, const int* __restrict__ deg,
                                             char* __restrict__ A,
                                             const int* __restrict__ ovf, const int* __restrict__ ovc,
                                             const int* __restrict__ ei, const int* __restrict__ et){
  int wid = (blockIdx.x * 256 + threadIdx.x) >> 6;
  int l = threadIdx.x & 63;
  if(wid >= NN) return;
  int d = __builtin_amdgcn_readfirstlane(wid);
  int dg = deg[d];
  int nb = dg < CAP ? dg : CAP;
  const char* Af = A + 2048;
  int voff = l * 4;
  float acc[16];
  #pragma unroll
  for(int j = 0; j < 16; j++) acc[j] = 0.f;
  int c0 = 0, c1 = 0, c2 = 0, c3 = 0, c4 = 0, c5 = 0, c6 = 0, c7 = 0;

#define ACCUM(T, W) { \
  float fx_ = bflo(W), fy_ = bfhi(W); \
  switch(T){ \
    case 0: acc[0]  += fx_; acc[1]  += fy_; c0++; break; \
    case 1: acc[2]  += fx_; acc[3]  += fy_; c1++; break; \
    case 2: acc[4]  += fx_; acc[5]  += fy_; c2++; break; \
    case 3: acc[6]  += fx_; acc[7]  += fy_; c3++; break; \
    case 4: acc[8]  += fx_; acc[9]  += fy_; c4++; break; \
    case 5: acc[10] += fx_; acc[11] += fy_; c5++; break; \
    case 6: acc[12] += fx_; acc[13] += fy_; c6++; break; \
    default: acc[14] += fx_; acc[15] += fy_; c7++; break; \
  } }

  int base = d * CAP;
  int i = 0;
  for(; i + 3 < nb; i += 4){
    int p0 = eb[base + i + 0];
    int p1 = eb[base + i + 1];
    int p2 = eb[base + i + 2];
    int p3 = eb[base + i + 3];
    unsigned w0 = *(const unsigned*)(Af + (size_t)(p0 & 0xffff) * RSB + voff);
    unsigned w1 = *(const unsigned*)(Af + (size_t)(p1 & 0xffff) * RSB + voff);
    unsigned w2 = *(const unsigned*)(Af + (size_t)(p2 & 0xffff) * RSB + voff);
    unsigned w3 = *(const unsigned*)(Af + (size_t)(p3 & 0xffff) * RSB + voff);
    ACCUM(p0 >> 16, w0);
    ACCUM(p1 >> 16, w1);
    ACCUM(p2 >> 16, w2);
    ACCUM(p3 >> 16, w3);
  }
  for(; i < nb; i++){
    int p0 = eb[base + i];
    unsigned w0 = *(const unsigned*)(Af + (size_t)(p0 & 0xffff) * RSB + voff);
    ACCUM(p0 >> 16, w0);
  }
  if(dg > CAP){
    int oc = *ovc; if(oc > OVCAP) oc = OVCAP;
    for(int k = 0; k < oc; k++){
      int e = ovf[k];
      if(ei[NE + e] != d) continue;
      int s = ei[e];
      int t0 = et[e];
      unsigned w0 = *(const unsigned*)(Af + (size_t)s * RSB + voff);
      ACCUM(t0, w0);
    }
  }
#undef ACCUM

#define STORE(TT, CT) { \
    float iv = 1.0f / (float)((CT) > 1 ? (CT) : 1); \
    unsigned o = (unsigned)f2bf(acc[2*(TT)] * iv) | ((unsigned)f2bf(acc[2*(TT)+1] * iv) << 16); \
    *(unsigned*)(A + (size_t)d * RSB + (TT) * 256 + voff) = o; \
  }
  STORE(0, c0); STORE(1, c1); STORE(2, c2); STORE(3, c3);
  STORE(4, c4); STORE(5, c5); STORE(6, c6); STORE(7, c7);
#undef STORE
}

// GEMM1: h = relu(A @ B1^T + b1) -> A tail (bf16).
// 2 waves/block, 32 rows/wave (2 row-frags share B-frags -> 16 MFMA / 10 loads per K-step).
__global__ __launch_bounds__(128) void gemm1_k(char* __restrict__ A, const s16x8* __restrict__ Bp,
                                               const float* __restrict__ rb, int nb0){
  int b = blockIdx.x;
  int v, rowbase, rowlim;
  if(b < nb0){ v = 0; rowbase = b * 64; rowlim = NN0; }
  else       { v = 1; rowbase = NN0 + (b - nb0) * 64; rowlim = NN; }
  int w = threadIdx.x >> 6, l = threadIdx.x & 63;
  int lm = l & 15, lk = l >> 4;
  int r0 = rowbase + w * 32 + lm;
  int r1 = r0 + 16;
  const char* a0 = A + (size_t)(r0 < NN ? r0 : NN - 1) * RSB;
  const char* a1 = A + (size_t)(r1 < NN ? r1 : NN - 1) * RSB;
  const s16x8* bv = Bp + (size_t)v * (KST * 8 * 64) + l;

  f32x4 acc[2][8];
  #pragma unroll
  for(int ri = 0; ri < 2; ri++)
    #pragma unroll
    for(int j = 0; j < 8; j++) acc[ri][j] = (f32x4)(0.f);

  #pragma unroll 2
  for(int ks = 0; ks < KST; ks++){
    s16x8 af0 = *(const s16x8*)(a0 + ks * 64 + lk * 16);
    s16x8 af1 = *(const s16x8*)(a1 + ks * 64 + lk * 16);
    const s16x8* bk = bv + (size_t)ks * (8 * 64);
    #pragma unroll
    for(int j = 0; j < 8; j++){
      s16x8 bj = bk[j * 64];
      acc[0][j] = __builtin_amdgcn_mfma_f32_16x16x32_bf16(af0, bj, acc[0][j], 0, 0, 0);
      acc[1][j] = __builtin_amdgcn_mfma_f32_16x16x32_bf16(af1, bj, acc[1][j], 0, 0, 0);
    }
  }
  #pragma unroll
  for(int j = 0; j < 8; j++){
    int col = j * 16 + lm;
    float bias = rb[v * HIDC + col];
    #pragma unroll
    for(int ri = 0; ri < 2; ri++){
      #pragma unroll
      for(int r = 0; r < 4; r++){
        int row = rowbase + w * 32 + ri * 16 + lk * 4 + r;
        if(row < rowlim){
          float hv = acc[ri][j][r] + bias;
          hv = hv > 0.f ? hv : 0.f;
          *(unsigned short*)(A + (size_t)row * RSB + 2048 + col * 2) = f2bf(hv);
        }
      }
    }
  }
}

// GEMM2 + bias + log_softmax -> out (f32). Same 32-rows/wave structure.
__global__ __launch_bounds__(128) void gemm2_k(const char* __restrict__ A, const s16x8* __restrict__ Bp,
                                               const float* __restrict__ rb, float* __restrict__ out, int nb0){
  int b = blockIdx.x;
  int v, rowbase, rowlim;
  if(b < nb0){ v = 0; rowbase = b * 64; rowlim = NN0; }
  else       { v = 1; rowbase = NN0 + (b - nb0) * 64; rowlim = NN; }
  int w = threadIdx.x >> 6, l = threadIdx.x & 63;
  int lm = l & 15, lk = l >> 4;
  int r0 = rowbase + w * 32 + lm;
  int r1 = r0 + 16;
  const char* a0 = A + (size_t)(r0 < NN ? r0 : NN - 1) * RSB;
  const char* a1 = A + (size_t)(r1 < NN ? r1 : NN - 1) * RSB;
  const s16x8* bv = Bp + (size_t)v * (KST * 3 * 64) + l;

  f32x4 acc[2][3];
  #pragma unroll
  for(int ri = 0; ri < 2; ri++)
    #pragma unroll
    for(int j = 0; j < 3; j++) acc[ri][j] = (f32x4)(0.f);

  #pragma unroll 2
  for(int ks = 0; ks < KST; ks++){
    s16x8 af0 = *(const s16x8*)(a0 + ks * 64 + lk * 16);
    s16x8 af1 = *(const s16x8*)(a1 + ks * 64 + lk * 16);
    const s16x8* bk = bv + (size_t)ks * (3 * 64);
    #pragma unroll
    for(int j = 0; j < 3; j++){
      s16x8 bj = bk[j * 64];
      acc[0][j] = __builtin_amdgcn_mfma_f32_16x16x32_bf16(af0, bj, acc[0][j], 0, 0, 0);
      acc[1][j] = __builtin_amdgcn_mfma_f32_16x16x32_bf16(af1, bj, acc[1][j], 0, 0, 0);
    }
  }

  #pragma unroll
  for(int ri = 0; ri < 2; ri++){
    float vals[3][4];
    #pragma unroll
    for(int j = 0; j < 3; j++){
      int col = j * 16 + lm;
      float bias = col < OUTC ? rb[v * OUTC + col] : 0.f;
      #pragma unroll
      for(int r = 0; r < 4; r++) vals[j][r] = acc[ri][j][r] + bias;
    }
    float mx[4], se[4];
    #pragma unroll
    for(int r = 0; r < 4; r++){
      float m = -1e30f;
      #pragma unroll
      for(int j = 0; j < 3; j++) if(j * 16 + lm < OUTC) m = fmaxf(m, vals[j][r]);
      mx[r] = m;
    }
    #pragma unroll
    for(int s = 1; s < 16; s <<= 1){
      #pragma unroll
      for(int r = 0; r < 4; r++) mx[r] = fmaxf(mx[r], __shfl_xor(mx[r], s, 64));
    }
    #pragma unroll
    for(int r = 0; r < 4; r++){
      float a = 0.f;
      #pragma unroll
      for(int j = 0; j < 3; j++) if(j * 16 + lm < OUTC) a += __expf(vals[j][r] - mx[r]);
      se[r] = a;
    }
    #pragma unroll
    for(int s = 1; s < 16; s <<= 1){
      #pragma unroll
      for(int r = 0; r < 4; r++) se[r] += __shfl_xor(se[r], s, 64);
    }
    #pragma unroll
    for(int r = 0; r < 4; r++) se[r] = logf(se[r]);
    #pragma unroll
    for(int j = 0; j < 3; j++){
      int col = j * 16 + lm;
      if(col >= OUTC) continue;
      #pragma unroll
      for(int r = 0; r < 4; r++){
        int row = rowbase + w * 32 + ri * 16 + lk * 4 + r;
        if(row < rowlim) out[(size_t)row * OUTC + col] = vals[j][r] - mx[r] - se[r];
      }
    }
  }
}

extern "C" void kernel_launch(void* const* d_in, const int* in_sizes, int n_in,
                              void* d_out, int out_size, void* d_ws, size_t ws_size,
                              hipStream_t stream){
  const float* x0  = (const float*)d_in[0];
  const float* e1  = (const float*)d_in[1];
  const float* rw1 = (const float*)d_in[2];
  const float* qw1 = (const float*)d_in[3];
  const float* qb1 = (const float*)d_in[4];
  const float* rw2 = (const float*)d_in[5];
  const float* qw2 = (const float*)d_in[6];
  const float* qb2 = (const float*)d_in[7];
  const int*   ei  = (const int*)d_in[8];
  const int*   et  = (const int*)d_in[9];
  const int*   ntp = (const int*)d_in[10];
  const int*   lix = (const int*)d_in[11];
  float* out = (float*)d_out;

  const size_t A_OFF   = 0;             // 50000*2304 = 115,200,000
  const size_t EB_OFF  = 115200000;     // 50000*64*4 = 12,800,000
  const size_t DEG_OFF = 128000000;     // 200,000
  const size_t OVC_OFF = 128200000;     // 256
  const size_t OVF_OFF = 128200256;     // 262,144
  const size_t BP1_OFF = 128462400;     // 589,824
  const size_t BP2_OFF = 129052224;     // 221,184
  const size_t TOTAL   = 129273408;
  if(ws_size < TOTAL) return;

  char* ws = (char*)d_ws;
  char*  A   = ws + A_OFF;
  int*   eb  = (int*)(ws + EB_OFF);
  int*   deg = (int*)(ws + DEG_OFF);
  int*   ovc = (int*)(ws + OVC_OFF);
  int*   ovf = (int*)(ws + OVF_OFF);
  short* Bp1 = (short*)(ws + BP1_OFF);
  short* Bp2 = (short*)(ws + BP2_OFF);

  int nb0 = (NN0 + 63) / 64;                    // 469
  int nb1 = (NN - NN0 + 63) / 64;               // 313

  hipMemsetAsync(deg, 0, 200000 + 256, stream);           // deg + ovc (adjacent)
  build_k<<<XB + FB + PB, 256, 0, stream>>>(x0, e1, ntp, lix, A, ei, et, deg, eb, ovf, ovc,
                                            rw1, qw1, rw2, qw2, Bp1, Bp2);
  agg_k<<<(NN * 64 + 255) / 256, 256, 0, stream>>>(eb, deg, A, ovf, ovc, ei, et);
  gemm1_k<<<nb0 + nb1, 128, 0, stream>>>(A, (const s16x8*)Bp1, qb1, nb0);
  agg_k<<<(NN * 64 + 255) / 256, 256, 0, stream>>>(eb, deg, A, ovf, ovc, ei, et);
  gemm2_k<<<nb0 + nb1, 128, 0, stream>>>(A, (const s16x8*)Bp2, qb2, out, nb0);
}